// Round 5
// baseline (320.261 us; speedup 1.0000x reference)
//
#include <hip/hip_runtime.h>

namespace {

constexpr float kAlpha = 0.025f;
constexpr float kC1 = 1.0e-4f;  // (0.01*1)^2
constexpr float kC2 = 9.0e-4f;  // (0.03*1)^2

constexpr int MPS = 72;  // bf16 row stride: 144 B, keeps b128 loads 16B-aligned

typedef __attribute__((ext_vector_type(8))) short short8;
typedef __attribute__((ext_vector_type(4))) float f32x4;

// LDS: mp 46.1 KB + hbT 23.0 KB + wfrag 4 KB + g1/red ~0.7 KB = 73.9 KB
// -> 2 blocks/CU
struct __align__(16) Smem {
  short mp[5][64 * MPS];   // bf16 pixel maps: x, y, x^2+y^2, xy, |x-y|
  short hbT[5][32 * MPS];  // bf16 H-conv results, transposed [out_col][row]
  int wfrag[4][64 * 4];    // lane-expanded W fragments, f = nt*2 + kt
  float g1[5 * 33];        // fp32 1D taps
  float red[4];
};

__device__ __forceinline__ unsigned f2bf(float f) {  // RNE fp32 -> bf16 bits
  unsigned u = __float_as_uint(f);
  return (u + 0x7FFFu + ((u >> 16) & 1u)) >> 16;
}
__device__ __forceinline__ unsigned pack2(float a, float b) {
  return f2bf(a) | (f2bf(b) << 16);
}
__device__ __forceinline__ float bf2f(unsigned b) {
  return __uint_as_float(b << 16);
}

// One sigma, full 33-tap band (zeros in W are free in the GEMM):
//  WH[k][n] = g[k-n] for k-n in [0,32]; H(64x32) = In(64x64) x WH
//  WV = WH^T (same lane fragments);     Out(32x32) = WV(32x64) x H
template <bool LAST>
__device__ __forceinline__ void do_sigma(Smem& sm, int s, int tid, f32x4& Pcs,
                                         f32x4& lumP, f32x4& l1v) {
  const int lane = tid & 63;
  const int w = tid >> 6;  // wave id
  const int quad = lane >> 4;
  const int l16 = lane & 15;

  __syncthreads();  // B_a: prev sigma's hbT/wfrag reads complete

  // ---- build lane-expanded W fragment f = w: B[k][n] layout ----
  {
    const int nt = w >> 1, kt = w & 1;
    const int n = nt * 16 + l16;
    int dw[4];
#pragma unroll
    for (int p = 0; p < 4; ++p) {
      unsigned lh[2];
#pragma unroll
      for (int h = 0; h < 2; ++h) {
        int k = kt * 32 + quad * 8 + 2 * p + h;
        int idx = k - n;  // tap index, valid [0,32]
        bool in = (idx >= 0) && (idx <= 32);
        int ic = min(max(idx, 0), 32);
        float g = sm.g1[s * 33 + ic];
        lh[h] = in ? f2bf(g) : 0u;
      }
      dw[p] = (int)(lh[0] | (lh[1] << 16));
    }
    *(int4*)(&sm.wfrag[w][lane * 4]) = make_int4(dw[0], dw[1], dw[2], dw[3]);
  }
  __syncthreads();  // B_b: wfrag ready

  short8 wf[2][2];
#pragma unroll
  for (int nt = 0; nt < 2; ++nt)
#pragma unroll
    for (int kt = 0; kt < 2; ++kt) {
      int4 t = *(const int4*)(&sm.wfrag[nt * 2 + kt][lane * 4]);
      wf[nt][kt] = *(short8*)&t;
    }

  // ---- H GEMM: wave w computes map w (all 64 rows x 32 cols, K=64) ----
  {
    const short* mpb = sm.mp[w];
#pragma unroll
    for (int mt = 0; mt < 4; ++mt) {
      const short* ap = mpb + (mt * 16 + l16) * MPS + quad * 8;
      int4 a0 = *(const int4*)(ap);
      int4 a1 = *(const int4*)(ap + 32);
#pragma unroll
      for (int nt = 0; nt < 2; ++nt) {
        f32x4 acc = {0.f, 0.f, 0.f, 0.f};
        acc = __builtin_amdgcn_mfma_f32_16x16x32_bf16(*(short8*)&a0,
                                                      wf[nt][0], acc, 0, 0, 0);
        acc = __builtin_amdgcn_mfma_f32_16x16x32_bf16(*(short8*)&a1,
                                                      wf[nt][1], acc, 0, 0, 0);
        // C/D: col=l16, row=quad*4+reg -> 4 consecutive rows, store transposed
        *(int2*)(&sm.hbT[w][(nt * 16 + l16) * MPS + mt * 16 + quad * 4]) =
            make_int2((int)pack2(acc[0], acc[1]), (int)pack2(acc[2], acc[3]));
      }
    }
    if (LAST) {  // map 4 (|x-y|): wave w takes mtile w
      const short* ap = sm.mp[4] + (w * 16 + l16) * MPS + quad * 8;
      int4 a0 = *(const int4*)(ap);
      int4 a1 = *(const int4*)(ap + 32);
#pragma unroll
      for (int nt = 0; nt < 2; ++nt) {
        f32x4 acc = {0.f, 0.f, 0.f, 0.f};
        acc = __builtin_amdgcn_mfma_f32_16x16x32_bf16(*(short8*)&a0,
                                                      wf[nt][0], acc, 0, 0, 0);
        acc = __builtin_amdgcn_mfma_f32_16x16x32_bf16(*(short8*)&a1,
                                                      wf[nt][1], acc, 0, 0, 0);
        *(int2*)(&sm.hbT[4][(nt * 16 + l16) * MPS + w * 16 + quad * 4]) =
            make_int2((int)pack2(acc[0], acc[1]), (int)pack2(acc[2], acc[3]));
      }
    }
  }
  __syncthreads();  // B_c: hbT ready

  // ---- V GEMM: wave quadrant (mtv = w>>1, ntv = w&1); A-frags = wf[mtv] ----
  const int mtv = w >> 1, ntv = w & 1;
  f32x4 va[LAST ? 5 : 4];
#pragma unroll
  for (int m = 0; m < (LAST ? 5 : 4); ++m) {
    const short* bp = sm.hbT[m] + (ntv * 16 + l16) * MPS + quad * 8;
    int4 b0 = *(const int4*)(bp);
    int4 b1 = *(const int4*)(bp + 32);
    f32x4 acc = {0.f, 0.f, 0.f, 0.f};
    acc = __builtin_amdgcn_mfma_f32_16x16x32_bf16(wf[mtv][0], *(short8*)&b0,
                                                  acc, 0, 0, 0);
    acc = __builtin_amdgcn_mfma_f32_16x16x32_bf16(wf[mtv][1], *(short8*)&b1,
                                                  acc, 0, 0, 0);
    va[m] = acc;
  }

  // ---- combine in registers: pixel (mtv*16+quad*4+r, ntv*16+l16) ----
  float corr = 1.f;
  if (LAST) {  // fp32 tap-sum compensation for bf16-rounded weights
    float se = 0.f, st = 0.f;
#pragma unroll
    for (int j = 0; j < 33; ++j) {
      float g = sm.g1[4 * 33 + j];
      se += g;
      st += bf2f(f2bf(g));
    }
    float r1 = se / st;
    corr = r1 * r1;
  }
#pragma unroll
  for (int r = 0; r < 4; ++r) {
    float mux = va[0][r], muy = va[1][r], m2 = va[2][r], mxy = va[3][r];
    float mux2 = mux * mux, muy2 = muy * muy, muxy = mux * muy;
    float cs = (2.f * (mxy - muxy) + kC2) / ((m2 - mux2 - muy2) + kC2);
    Pcs[r] *= cs;
    if (LAST) {
      lumP[r] = ((2.f * muxy + kC1) / (mux2 + muy2 + kC1)) * Pcs[r];
      l1v[r] = va[4][r] * corr;
    }
  }
}

__global__ __launch_bounds__(256, 2) void msssim_l1_kernel(
    const float* __restrict__ x, const float* __restrict__ y,
    const float* __restrict__ gm, float* __restrict__ out) {
  __shared__ Smem sm;
  const int tid = threadIdx.x;

  // 1D taps: mask = outer(g,g) -> g[j] = m[16][j] / sqrt(m[16][16])
  if (tid < 165) {
    int s = tid / 33;
    int j = tid - s * 33;
    float c = gm[s * 1089 + 16 * 33 + 16];
    sm.g1[tid] = gm[s * 1089 + 16 * 33 + j] * rsqrtf(c);
  }

  // 64x64 halo patch, zero-padded; build 5 bf16 pixel maps
  const float* xb = x + blockIdx.z * (512 * 512);
  const float* yb = y + blockIdx.z * (512 * 512);
  const int rb = blockIdx.y * 32 - 16;
  const int cb = blockIdx.x * 32 - 16;
  for (int f = tid; f < 1024; f += 256) {
    int pr = f >> 4;
    int pc = (f & 15) << 2;
    int gr = rb + pr, gc = cb + pc;
    float4 vx = make_float4(0.f, 0.f, 0.f, 0.f);
    float4 vy = vx;
    if (gr >= 0 && gr < 512 && gc >= 0 && gc < 512) {
      vx = *(const float4*)(xb + gr * 512 + gc);
      vy = *(const float4*)(yb + gr * 512 + gc);
    }
    const int base = pr * MPS + pc;  // shorts; byte offset 8-aligned
    *(int2*)(&sm.mp[0][base]) =
        make_int2((int)pack2(vx.x, vx.y), (int)pack2(vx.z, vx.w));
    *(int2*)(&sm.mp[1][base]) =
        make_int2((int)pack2(vy.x, vy.y), (int)pack2(vy.z, vy.w));
    float s0 = fmaf(vx.x, vx.x, vy.x * vy.x), s1 = fmaf(vx.y, vx.y, vy.y * vy.y);
    float s2 = fmaf(vx.z, vx.z, vy.z * vy.z), s3 = fmaf(vx.w, vx.w, vy.w * vy.w);
    *(int2*)(&sm.mp[2][base]) = make_int2((int)pack2(s0, s1), (int)pack2(s2, s3));
    *(int2*)(&sm.mp[3][base]) = make_int2((int)pack2(vx.x * vy.x, vx.y * vy.y),
                                          (int)pack2(vx.z * vy.z, vx.w * vy.w));
    *(int2*)(&sm.mp[4][base]) =
        make_int2((int)pack2(fabsf(vx.x - vy.x), fabsf(vx.y - vy.y)),
                  (int)pack2(fabsf(vx.z - vy.z), fabsf(vx.w - vy.w)));
  }

  f32x4 Pcs = {1.f, 1.f, 1.f, 1.f};
  f32x4 lumP = {0.f, 0.f, 0.f, 0.f};
  f32x4 l1v = {0.f, 0.f, 0.f, 0.f};

  do_sigma<false>(sm, 0, tid, Pcs, lumP, l1v);
  do_sigma<false>(sm, 1, tid, Pcs, lumP, l1v);
  do_sigma<false>(sm, 2, tid, Pcs, lumP, l1v);
  do_sigma<false>(sm, 3, tid, Pcs, lumP, l1v);
  do_sigma<true>(sm, 4, tid, Pcs, lumP, l1v);

  // loss_mix = alpha*(1 - lum*PIcs) + (1-alpha)*gaussian_l1 ; out = 20*mean
  float lsum = 0.f;
#pragma unroll
  for (int r = 0; r < 4; ++r)
    lsum += kAlpha * (1.f - lumP[r]) + (1.f - kAlpha) * l1v[r];
#pragma unroll
  for (int off = 32; off > 0; off >>= 1) lsum += __shfl_down(lsum, off, 64);
  if ((tid & 63) == 0) sm.red[tid >> 6] = lsum;
  __syncthreads();
  if (tid == 0) {
    float t = sm.red[0] + sm.red[1] + sm.red[2] + sm.red[3];
    atomicAdd(out, t * (20.f / (16.f * 512.f * 512.f)));
  }
}

}  // namespace

extern "C" void kernel_launch(void* const* d_in, const int* in_sizes, int n_in,
                              void* d_out, int out_size, void* d_ws,
                              size_t ws_size, hipStream_t stream) {
  (void)in_sizes;
  (void)n_in;
  (void)d_ws;
  (void)ws_size;
  (void)out_size;
  const float* x = (const float*)d_in[0];
  const float* y = (const float*)d_in[1];
  const float* gm = (const float*)d_in[2];
  float* out = (float*)d_out;
  hipMemsetAsync(out, 0, sizeof(float), stream);
  dim3 grid(16, 16, 16);
  msssim_l1_kernel<<<grid, dim3(256), 0, stream>>>(x, y, gm, out);
}